// Round 3
// baseline (138.753 us; speedup 1.0000x reference)
//
#include <hip/hip_runtime.h>
#include <hip/hip_bf16.h>

// STDP via the antisymmetric-kernel identity (verified R6, absmax 9.8e-4):
//   out[q,p] = 4w(1-w) * A_SCALE * sum_{b,t} post_s[b,t,q] * Z[b,t,p]
//   Z = pre_tr - pre_rt;  tr = causal decay scan, rt = anti-causal scan.
//   AT[q][b*128+t] = post_spikes (bf16);  BT[p][b*128+t] = Z (bf16)

typedef __attribute__((ext_vector_type(8))) short bf16x8;
typedef __attribute__((ext_vector_type(4))) float f32x4;

#define GN 2048
#define KTOT 2048
#define A_SCALE (0.01f / 16.0f)
#define FST 68   // fbuf dword stride (16B-aligned float4 rows)
#define ZST 66   // zbuf elem stride (8B-aligned packed writes)
#define RST 36   // reduce dword row stride: quad -> 16*quad mod 32, 2-way = free

#define GLOAD_LDS16(gp, lp) \
    __builtin_amdgcn_global_load_lds((const __attribute__((address_space(1))) void*)(gp), \
                                     (__attribute__((address_space(3))) void*)(lp), 16, 0, 0)

__device__ __forceinline__ unsigned bf16bits(float x) {
    __hip_bfloat16 h = __float2bfloat16(x);
    return (unsigned)*(unsigned short*)&h;
}

// ---------------------------------------------------------------------------
// Kernel 1: transpose (+ double scan for the pre side), float4 global loads.
// grid (32, 16, 2), block 256 (4 waves). z=0: post -> AT, z=1: pre -> BT.
// zbuf overlays fbuf.  LDS 34816 B -> 4 blocks/CU.  (~12 us, near HBM floor)
// ---------------------------------------------------------------------------
__global__ __launch_bounds__(256, 4) void trace_kernel(
    const float* __restrict__ pre,
    const float* __restrict__ post,
    const int* __restrict__ dtp,
    __hip_bfloat16* __restrict__ AT,
    __hip_bfloat16* __restrict__ BT)
{
    __shared__ float fbuf[128 * FST];                    // 34816 B, t-major fp32
    __hip_bfloat16* zbuf = (__hip_bfloat16*)fbuf;        // overlay, t-major bf16

    const int tid = threadIdx.x;
    const int w   = tid >> 6;    // wave 0..3
    const int l   = tid & 63;
    const int nq  = tid & 15;    // float4 group along n
    const int tl  = tid >> 4;    // t-row within a 16-row pass
    const int n0  = blockIdx.x * 64;
    const int b   = blockIdx.y;
    const int a   = blockIdx.z;  // 0: post->AT, 1: pre->BT

    int di = dtp[0];
    float dtf = (di > 0 && di < 1000000) ? (float)di : *(const float*)dtp;
    const float decay = __expf(-dtf / 20.0f);

    if (a == 0) {
        #pragma unroll
        for (int pass = 0; pass < 8; ++pass) {
            const int t = pass * 16 + tl;
            float4 v = *(const float4*)&post[((size_t)b * 128 + t) * GN + n0 + 4 * nq];
            uint2 pk;
            pk.x = bf16bits(v.x) | (bf16bits(v.y) << 16);
            pk.y = bf16bits(v.z) | (bf16bits(v.w) << 16);
            *(uint2*)&zbuf[t * ZST + 4 * nq] = pk;
        }
        __syncthreads();
    } else {
        #pragma unroll
        for (int pass = 0; pass < 8; ++pass) {
            const int t = pass * 16 + tl;
            float4 v = *(const float4*)&pre[((size_t)b * 128 + t) * GN + n0 + 4 * nq];
            *(float4*)&fbuf[t * FST + 4 * nq] = v;
        }
        __syncthreads();

        const int t0 = 32 * w;   // this wave's t segment [t0, t0+32)
        float carry = 0.0f;
        #pragma unroll 8
        for (int t = 1; t < t0; ++t)
            carry = decay * carry + fbuf[t * FST + l];
        float z[32];
        #pragma unroll
        for (int j = 0; j < 32; ++j) {
            const int t = t0 + j;
            if (t >= 1) carry = decay * carry + fbuf[t * FST + l];
            z[j] = carry;                     // tr (t=0 -> 0)
        }
        float bc = 0.0f;
        #pragma unroll 8
        for (int t = 127; t >= t0 + 32; --t)
            bc = decay * bc + fbuf[t * FST + l];
        #pragma unroll
        for (int j = 31; j >= 0; --j) {
            const int t = t0 + j;
            bc = decay * bc + fbuf[t * FST + l];
            if (t >= 1) z[j] -= bc;           // Z = tr - rt   (Z[0] = 0)
        }
        __syncthreads();   // all waves done reading fbuf before zbuf overlay
        #pragma unroll
        for (int j = 0; j < 32; ++j)
            zbuf[(t0 + j) * ZST + l] = __float2bfloat16(z[j]);
        __syncthreads();
    }

    __hip_bfloat16* dst = (a == 0) ? AT : BT;
    #pragma unroll
    for (int j = 0; j < 4; ++j) {
        const int c  = tid + 256 * j;   // 0..1023
        const int n  = c >> 4;          // 0..63
        const int tc = c & 15;          // 8-t chunk
        unsigned int vv[8];
        #pragma unroll
        for (int i = 0; i < 8; ++i)
            vv[i] = *(const unsigned short*)&zbuf[(8 * tc + i) * ZST + n];
        uint4 pk;
        pk.x = vv[0] | (vv[1] << 16);
        pk.y = vv[2] | (vv[3] << 16);
        pk.z = vv[4] | (vv[5] << 16);
        pk.w = vv[6] | (vv[7] << 16);
        *(uint4*)(dst + (size_t)(n0 + n) * KTOT + b * 128 + tc * 8) = pk;
    }
}

// ---------------------------------------------------------------------------
// Kernel 2: out = 4w(1-w)*A_SCALE * (AT * BT^T), IN-BLOCK split-K.
// R3 redesign (post-mortem of R2's 47 us: LDS-pipe + barrier-convoy bound,
// bank conflicts +4 cyc/ds_read from the 4-slot swizzle):
//   * B is NOT staged in LDS.  Each wave reads its B fragments directly from
//     global (BT) into VGPRs: per read, 16 rows x 64 B contiguous -> clean
//     64 B L2 sectors.  A column-chunked XCD swizzle (xcd x owns p-cols
//     4x..4x+3 = 1 MB of BT) keeps B L2-resident -> ~200 cyc loads, fully
//     covered by the ds_read+MFMA phase.  B needs NO barrier protection.
//   * LDS holds only A: 2 grp x 2 buf x 16 KB = 64 KB -> BK=64 double-buffer
//     fits while keeping 2 blocks/CU.  BK=64 restores the PROVEN 8-slot XOR
//     swizzle at 128 B rows (2-way = free; R2's 64 B rows forced 4-slot =
//     4-way = +4 cyc/read, measured 3.1M conflict cycles).
//   * LDS traffic drops 2.25 MB -> 1.5 MB per block (~10 us pipe floor).
//   * Barriers 32 -> 16 per loop; each drain's A-prefetch was issued a full
//     compute phase (~1000 cyc) earlier -> ~0 stall.  B loads are issued
//     FIRST in the body so the compiler's FIFO vmcnt wait for them does not
//     force the A-stage (issued after) to complete early.
// K accumulation order identical to the proven baseline (kk=0 then kk=32,
// k0 ascending) -> absmax unchanged.
// Epilogue reduce unchanged (proven): grp 1 parks acc at RST=36 (2-way =
// free), grp 0 adds, applies softbound, writes.
// ---------------------------------------------------------------------------
__global__ __launch_bounds__(512) void stdp_gemm(
    const __hip_bfloat16* __restrict__ AT,
    const __hip_bfloat16* __restrict__ BT,
    const float* __restrict__ W,
    float* __restrict__ out)
{
    __shared__ alignas(16) char smem[65536];   // 2 grp x 2 buf x 16 KB A; reduce overlay

    const int tid  = threadIdx.x;
    const int lane = tid & 63;
    const int wv8  = tid >> 6;          // wave 0..7
    const int grp  = wv8 >> 2;          // K-half 0/1
    const int wv   = wv8 & 3;           // wave within group
    const int wm   = (wv >> 1) * 64;    // {0,64}
    const int wn   = (wv & 1) * 32;     // {0,32}

    // Column-chunked XCD swizzle (bijective, 512 = 8*64): xcd x gets p-cols
    // {4x..4x+3} x all 16 q-rows.  B working set/XCD = 4 x 256 KB = 1 MB
    // (L2-resident for the direct B reads); consecutive blocks on an XCD
    // share a q-row, so the A panel stays L2-warm for the staging loads.
    const int hw = blockIdx.y * 32 + blockIdx.x;
    const int xc = hw & 7;
    const int rr = hw >> 3;              // 0..63 within XCD
    const int CN = (xc * 4 + (rr & 3)) * 64;   // p base
    const int RM = (rr >> 2) * 128;            // q base

    const int l15  = lane & 15;
    const int quad = lane >> 4;

    char* gbase = smem + grp * 32768;    // this group's 2 ping-pong A buffers
    const int K0 = grp * 1024;

    // B fragment base: row CN+wn+l15, k chunk quad (16 B).  j adds 16 rows,
    // kk=32 adds 32 elems, step h adds 64 elems.
    const __hip_bfloat16* Bb = BT + (size_t)(CN + wn + l15) * KTOT + K0 + quad * 8;

    // A staging: 128 rows x 8 chunks of 16 B = 1024 chunks over (it, wv, lane).
    // LDS slot (c&7) holds k-chunk (c&7)^(row&7); source pre-swizzled (m173).
#define STAGE(buf, kofs) do {                                                  \
        char* Ab_ = gbase + (buf) * 16384;                                     \
        _Pragma("unroll")                                                      \
        for (int it_ = 0; it_ < 4; ++it_) {                                    \
            const int cbase_ = it_ * 256 + wv * 64;  /* wave-uniform */        \
            const int c_     = cbase_ + lane;                                  \
            const int row_   = c_ >> 3;                                        \
            const int kc_    = (c_ & 7) ^ (row_ & 7);                          \
            GLOAD_LDS16(AT + (size_t)(RM + row_) * KTOT + (kofs) + kc_ * 8,    \
                        Ab_ + cbase_ * 16);                                    \
        } } while (0)

    f32x4 acc[4][2] = {};

    // prologue: stage K-step 0 into buf 0
    STAGE(0, K0);
    __syncthreads();

    #pragma unroll 2
    for (int h = 0; h < 16; ++h) {
        const int cur  = h & 1;
        const int kofs = K0 + h * 64;

        // B fragments straight from global (issued first: FIFO vmcnt means
        // waiting for these does not wait for the A-stage issued below).
        bf16x8 b00 = *(const bf16x8*)(Bb + h * 64);
        bf16x8 b01 = *(const bf16x8*)(Bb + 16 * KTOT + h * 64);
        bf16x8 b10 = *(const bf16x8*)(Bb + 32 + h * 64);
        bf16x8 b11 = *(const bf16x8*)(Bb + 16 * KTOT + 32 + h * 64);

        if (h < 15) STAGE(cur ^ 1, kofs + 64);   // prefetch next K-step

        const __hip_bfloat16* Ag = (const __hip_bfloat16*)(gbase + cur * 16384);

        bf16x8 af[4];
        // kk = 0: slots jg = quad
        #pragma unroll
        for (int i = 0; i < 4; ++i) {
            const int mr = wm + i * 16 + l15;
            af[i] = *(const bf16x8*)(Ag + mr * 64 + ((quad ^ (mr & 7)) * 8));
        }
        #pragma unroll
        for (int i = 0; i < 4; ++i) {
            acc[i][0] = __builtin_amdgcn_mfma_f32_16x16x32_bf16(af[i], b00, acc[i][0], 0, 0, 0);
            acc[i][1] = __builtin_amdgcn_mfma_f32_16x16x32_bf16(af[i], b01, acc[i][1], 0, 0, 0);
        }
        // kk = 32: slots jg = 4 + quad
        #pragma unroll
        for (int i = 0; i < 4; ++i) {
            const int mr = wm + i * 16 + l15;
            af[i] = *(const bf16x8*)(Ag + mr * 64 + (((4 + quad) ^ (mr & 7)) * 8));
        }
        #pragma unroll
        for (int i = 0; i < 4; ++i) {
            acc[i][0] = __builtin_amdgcn_mfma_f32_16x16x32_bf16(af[i], b10, acc[i][0], 0, 0, 0);
            acc[i][1] = __builtin_amdgcn_mfma_f32_16x16x32_bf16(af[i], b11, acc[i][1], 0, 0, 0);
        }

        __syncthreads();   // drain this wave's A-prefetch; release buffers
    }
#undef STAGE

    // -------- in-LDS split-K reduction + fused epilogue --------
    // C/D layout: acc[i][j][r] -> local row i*16+quad*4+r, local col j*16+l15
    float* red = (float*)smem;                 // 4 waves x 64 rows x RST dwords
    const int rbase = wv * 64 * RST;           // 9216 B/wave, 36864 B total
    if (grp == 1) {
        #pragma unroll
        for (int i = 0; i < 4; ++i)
            #pragma unroll
            for (int r = 0; r < 4; ++r)
                #pragma unroll
                for (int j = 0; j < 2; ++j)
                    red[rbase + (i * 16 + quad * 4 + r) * RST + j * 16 + l15] = acc[i][j][r];
    }
    __syncthreads();
    if (grp == 0) {
        #pragma unroll
        for (int i = 0; i < 4; ++i) {
            #pragma unroll
            for (int r = 0; r < 4; ++r) {
                const int q = RM + wm + i * 16 + quad * 4 + r;
                #pragma unroll
                for (int j = 0; j < 2; ++j) {
                    const int p = CN + wn + j * 16 + l15;
                    float v = acc[i][j][r]
                            + red[rbase + (i * 16 + quad * 4 + r) * RST + j * 16 + l15];
                    const float w  = W[(size_t)q * GN + p];
                    const float wf = 4.0f * w * (1.0f - w);
                    out[(size_t)q * GN + p] = wf * A_SCALE * v;
                }
            }
        }
    }
}

extern "C" void kernel_launch(void* const* d_in, const int* in_sizes, int n_in,
                              void* d_out, int out_size, void* d_ws, size_t ws_size,
                              hipStream_t stream) {
    const float* W    = (const float*)d_in[0];  // [2048][2048]
    const float* pre  = (const float*)d_in[1];  // [16][128][2048]
    const float* post = (const float*)d_in[2];  // [16][128][2048]
    const int*   dt   = (const int*)d_in[3];
    float* out = (float*)d_out;

    __hip_bfloat16* AT = (__hip_bfloat16*)d_ws;            // 8 MB
    __hip_bfloat16* BT = AT + (size_t)GN * KTOT;           // +8 MB

    trace_kernel<<<dim3(32, 16, 2), 256, 0, stream>>>(pre, post, dt, AT, BT);
    stdp_gemm<<<dim3(32, 16), 512, 0, stream>>>(AT, BT, W, out);
}

// Round 4
// 119.303 us; speedup vs baseline: 1.1630x; 1.1630x over previous
//
#include <hip/hip_runtime.h>
#include <hip/hip_bf16.h>

// STDP via the antisymmetric-kernel identity (verified R6, absmax 9.8e-4):
//   out[q,p] = 4w(1-w) * A_SCALE * sum_{b,t} post_s[b,t,q] * Z[b,t,p]
//   Z = pre_tr - pre_rt;  tr = causal decay scan, rt = anti-causal scan.
//   AT[q][b*128+t] = post_spikes (bf16);  BT[p][b*128+t] = Z (bf16)

typedef __attribute__((ext_vector_type(8))) short bf16x8;
typedef __attribute__((ext_vector_type(16))) float f32x16;

#define GN 2048
#define KTOT 2048
#define A_SCALE (0.01f / 16.0f)
#define FST 68   // fbuf dword stride (16B-aligned float4 rows)
#define ZST 66   // zbuf elem stride (8B-aligned packed writes)

#define GLOAD_LDS16(gp, lp) \
    __builtin_amdgcn_global_load_lds((const __attribute__((address_space(1))) void*)(gp), \
                                     (__attribute__((address_space(3))) void*)(lp), 16, 0, 0)

__device__ __forceinline__ unsigned bf16bits(float x) {
    __hip_bfloat16 h = __float2bfloat16(x);
    return (unsigned)*(unsigned short*)&h;
}

// ---------------------------------------------------------------------------
// Kernel 1: transpose (+ double scan for the pre side), float4 global loads.
// grid (32, 16, 2), block 256 (4 waves). z=0: post -> AT, z=1: pre -> BT.
// zbuf overlays fbuf.  LDS 34816 B -> 4 blocks/CU.  (~12 us, near HBM floor)
// UNCHANGED from the proven baseline.
// ---------------------------------------------------------------------------
__global__ __launch_bounds__(256, 4) void trace_kernel(
    const float* __restrict__ pre,
    const float* __restrict__ post,
    const int* __restrict__ dtp,
    __hip_bfloat16* __restrict__ AT,
    __hip_bfloat16* __restrict__ BT)
{
    __shared__ float fbuf[128 * FST];                    // 34816 B, t-major fp32
    __hip_bfloat16* zbuf = (__hip_bfloat16*)fbuf;        // overlay, t-major bf16

    const int tid = threadIdx.x;
    const int w   = tid >> 6;    // wave 0..3
    const int l   = tid & 63;
    const int nq  = tid & 15;    // float4 group along n
    const int tl  = tid >> 4;    // t-row within a 16-row pass
    const int n0  = blockIdx.x * 64;
    const int b   = blockIdx.y;
    const int a   = blockIdx.z;  // 0: post->AT, 1: pre->BT

    int di = dtp[0];
    float dtf = (di > 0 && di < 1000000) ? (float)di : *(const float*)dtp;
    const float decay = __expf(-dtf / 20.0f);

    if (a == 0) {
        #pragma unroll
        for (int pass = 0; pass < 8; ++pass) {
            const int t = pass * 16 + tl;
            float4 v = *(const float4*)&post[((size_t)b * 128 + t) * GN + n0 + 4 * nq];
            uint2 pk;
            pk.x = bf16bits(v.x) | (bf16bits(v.y) << 16);
            pk.y = bf16bits(v.z) | (bf16bits(v.w) << 16);
            *(uint2*)&zbuf[t * ZST + 4 * nq] = pk;
        }
        __syncthreads();
    } else {
        #pragma unroll
        for (int pass = 0; pass < 8; ++pass) {
            const int t = pass * 16 + tl;
            float4 v = *(const float4*)&pre[((size_t)b * 128 + t) * GN + n0 + 4 * nq];
            *(float4*)&fbuf[t * FST + 4 * nq] = v;
        }
        __syncthreads();

        const int t0 = 32 * w;   // this wave's t segment [t0, t0+32)
        float carry = 0.0f;
        #pragma unroll 8
        for (int t = 1; t < t0; ++t)
            carry = decay * carry + fbuf[t * FST + l];
        float z[32];
        #pragma unroll
        for (int j = 0; j < 32; ++j) {
            const int t = t0 + j;
            if (t >= 1) carry = decay * carry + fbuf[t * FST + l];
            z[j] = carry;                     // tr (t=0 -> 0)
        }
        float bc = 0.0f;
        #pragma unroll 8
        for (int t = 127; t >= t0 + 32; --t)
            bc = decay * bc + fbuf[t * FST + l];
        #pragma unroll
        for (int j = 31; j >= 0; --j) {
            const int t = t0 + j;
            bc = decay * bc + fbuf[t * FST + l];
            if (t >= 1) z[j] -= bc;           // Z = tr - rt   (Z[0] = 0)
        }
        __syncthreads();   // all waves done reading fbuf before zbuf overlay
        #pragma unroll
        for (int j = 0; j < 32; ++j)
            zbuf[(t0 + j) * ZST + l] = __float2bfloat16(z[j]);
        __syncthreads();
    }

    __hip_bfloat16* dst = (a == 0) ? AT : BT;
    #pragma unroll
    for (int j = 0; j < 4; ++j) {
        const int c  = tid + 256 * j;   // 0..1023
        const int n  = c >> 4;          // 0..63
        const int tc = c & 15;          // 8-t chunk
        unsigned int vv[8];
        #pragma unroll
        for (int i = 0; i < 8; ++i)
            vv[i] = *(const unsigned short*)&zbuf[(8 * tc + i) * ZST + n];
        uint4 pk;
        pk.x = vv[0] | (vv[1] << 16);
        pk.y = vv[2] | (vv[3] << 16);
        pk.z = vv[4] | (vv[5] << 16);
        pk.w = vv[6] | (vv[7] << 16);
        *(uint4*)(dst + (size_t)(n0 + n) * KTOT + b * 128 + tc * 8) = pk;
    }
}

// ---------------------------------------------------------------------------
// Kernel 2: out = 4w(1-w)*A_SCALE * (AT * BT^T).
// R4: TRUE T3+T4 (counted vmcnt, never-drain).  Post-mortem chain:
//   baseline 35.5us (drain-0 each iter, covered only by 2-blocks/CU),
//   R2 47us (BK=32 bank conflicts), R3 52us (B-direct vmem stalls).
//   All three drained vmcnt to 0 every barrier -> convoy slop ~2600cyc/iter.
// New structure: NO split-K.  512 blocks x 128x64 tile, 8 waves = 4x2 grid,
// each wave owns one 32x32 output tile via mfma_f32_32x32x16_bf16
// (4 MFMA + 8 ds_read_b128 per BK=64 step), K=2048 in 32 steps.
// LDS: THREE 24KB buffers (A 16K + B 8K) = 72KB -> 2 blocks/CU.
// Per iter h: STAGE(tile h+2) ; compute(tile h) ; s_waitcnt vmcnt(3) ;
// s_barrier.  The wait covers only tile h+1's 3 loads/wave, issued TWO
// compute phases earlier -> effectively free; vmcnt never drains to 0
// except the tail step (h=30).  Safety: stage(h+2) overwrites tile h-1,
// whose reads all completed before barrier(h-1); ready(h+1) holds because
// every wave passes its own vmcnt(3) before barrier(h).  Barriers are
// uniform across all 512 threads -> no divergent-barrier hang.
// sched_barrier(0) after each barrier pins ds_reads (guide rule #18).
// 8-slot XOR swizzle on 128B rows (proven conflict-free, R3: 0 conflicts).
// No split-K -> the 36KB LDS reduce + 2 barriers vanish; epilogue writes
// straight from acc (C/D layout col=lane&31, row=(r&3)+8*(r>>2)+4*(lane>>5),
// guide-verified m74/m101).
// ---------------------------------------------------------------------------
__global__ __launch_bounds__(512, 4) void stdp_gemm(
    const __hip_bfloat16* __restrict__ AT,
    const __hip_bfloat16* __restrict__ BT,
    const float* __restrict__ W,
    float* __restrict__ out)
{
    __shared__ alignas(16) char smem[73728];   // 3 x (A 16384 + B 8192)

    const int tid  = threadIdx.x;
    const int lane = tid & 63;
    const int wv8  = tid >> 6;          // wave 0..7
    const int wr   = wv8 >> 1;          // row-block 0..3  (32 rows each)
    const int wc   = wv8 & 1;           // col-block 0..1  (32 cols each)
    const int RM   = blockIdx.y * 128;  // q base
    const int CN   = blockIdx.x * 64;   // p base
    const int l31  = lane & 31;
    const int hi   = lane >> 5;

    // ---- staging assignment: 3 gload_lds per wave per tile ----
    // A: 128 rows x 8 chunks(16B) = 1024 chunks; chunk c = it*512 + wv8*64 + lane.
    // B:  64 rows x 8 chunks      =  512 chunks; chunk c =            wv8*64 + lane.
    // LDS slot (c&7) of row r holds k-chunk (c&7)^(r&7) (source pre-swizzled).
    const int cS   = wv8 * 64 + lane;   // 0..511
    const int rS   = cS >> 3;           // 0..63
    const int sS   = cS & 7;
    const int kc0  = sS ^ (rS & 7);
    const int kc1  = sS ^ ((rS + 64) & 7);
    const __hip_bfloat16* srcA0 = AT + (size_t)(RM + rS)      * KTOT + kc0 * 8;
    const __hip_bfloat16* srcA1 = AT + (size_t)(RM + rS + 64) * KTOT + kc1 * 8;
    const __hip_bfloat16* srcB  = BT + (size_t)(CN + rS)      * KTOT + kc0 * 8;
    const int dS = wv8 * 1024;          // (wv8*64 chunks)*16B, wave-uniform base

#define STAGE(BUF, kstep) do {                                   \
        char* bb_ = (BUF);                                       \
        const int ke_ = (kstep) * 64;                            \
        GLOAD_LDS16(srcA0 + ke_, bb_ + dS);                      \
        GLOAD_LDS16(srcA1 + ke_, bb_ + 8192 + dS);               \
        GLOAD_LDS16(srcB  + ke_, bb_ + 16384 + dS);              \
    } while (0)

    // ---- compute: one 32x32 tile per wave, 4 x mfma_32x32x16 per BK=64 ----
    const int ra = wr * 32 + l31;       // A row this lane reads
    const int rb = wc * 32 + l31;       // B row this lane reads

    f32x16 acc = {};

#define COMPUTE(BUF) do {                                                       \
        const __hip_bfloat16* Ab_ = (const __hip_bfloat16*)(BUF);               \
        const __hip_bfloat16* Bb_ = (const __hip_bfloat16*)((BUF) + 16384);     \
        bf16x8 av_[4], bv_[4];                                                  \
        _Pragma("unroll")                                                       \
        for (int ks_ = 0; ks_ < 4; ++ks_) {                                     \
            const int ja_ = (ks_ * 2 + hi) ^ (ra & 7);                          \
            const int jb_ = (ks_ * 2 + hi) ^ (rb & 7);                          \
            av_[ks_] = *(const bf16x8*)(Ab_ + ra * 64 + ja_ * 8);               \
            bv_[ks_] = *(const bf16x8*)(Bb_ + rb * 64 + jb_ * 8);               \
        }                                                                       \
        _Pragma("unroll")                                                       \
        for (int ks_ = 0; ks_ < 4; ++ks_)                                       \
            acc = __builtin_amdgcn_mfma_f32_32x32x16_bf16(av_[ks_], bv_[ks_],   \
                                                          acc, 0, 0, 0);        \
    } while (0)

#define WAITBAR(N) do {                                          \
        asm volatile("s_waitcnt vmcnt(" #N ")" ::: "memory");    \
        __builtin_amdgcn_s_barrier();                            \
        __builtin_amdgcn_sched_barrier(0);                       \
    } while (0)

    char* B0 = smem;
    char* B1 = smem + 24576;
    char* B2 = smem + 49152;

    // prologue: tiles 0 and 1 in flight; publish tile 0
    STAGE(B0, 0);
    STAGE(B1, 1);
    WAITBAR(3);                          // tile 0 landed (3 = tile 1 in flight)

    // steady state: h = 0..29, buffers cycle (0,1,2); wait always vmcnt(3)
    for (int hb = 0; hb < 30; hb += 3) {
        STAGE(B2, hb + 2); COMPUTE(B0); WAITBAR(3);
        STAGE(B0, hb + 3); COMPUTE(B1); WAITBAR(3);
        STAGE(B1, hb + 4); COMPUTE(B2); WAITBAR(3);
    }
    // h = 30: nothing left to stage; tail drain (the only vmcnt(0))
    COMPUTE(B0);
    WAITBAR(0);                          // tile 31 fully landed
    // h = 31: last tile; no barrier needed after (epilogue touches no LDS)
    COMPUTE(B1);

#undef STAGE
#undef COMPUTE
#undef WAITBAR

    // -------- epilogue: softbound + write, straight from acc --------
    // C/D layout (32x32): col = lane&31, row = (r&3) + 8*(r>>2) + 4*hi
    const int p = CN + wc * 32 + l31;
    #pragma unroll
    for (int r = 0; r < 16; ++r) {
        const int q = RM + wr * 32 + (r & 3) + 8 * (r >> 2) + 4 * hi;
        const float w  = W[(size_t)q * GN + p];
        const float wf = 4.0f * w * (1.0f - w);
        out[(size_t)q * GN + p] = wf * A_SCALE * acc[r];
    }
}

extern "C" void kernel_launch(void* const* d_in, const int* in_sizes, int n_in,
                              void* d_out, int out_size, void* d_ws, size_t ws_size,
                              hipStream_t stream) {
    const float* W    = (const float*)d_in[0];  // [2048][2048]
    const float* pre  = (const float*)d_in[1];  // [16][128][2048]
    const float* post = (const float*)d_in[2];  // [16][128][2048]
    const int*   dt   = (const int*)d_in[3];
    float* out = (float*)d_out;

    __hip_bfloat16* AT = (__hip_bfloat16*)d_ws;            // 8 MB
    __hip_bfloat16* BT = AT + (size_t)GN * KTOT;           // +8 MB

    trace_kernel<<<dim3(32, 16, 2), 256, 0, stream>>>(pre, post, dt, AT, BT);
    stdp_gemm<<<dim3(32, 16), 512, 0, stream>>>(AT, BT, W, out);
}